// Round 5
// baseline (480.270 us; speedup 1.0000x reference)
//
#include <hip/hip_runtime.h>
#include <stdint.h>

#define N_NODES 100000
#define N_EDGES 320000
#define DIM 256
#define BN_EPS 1e-5f

typedef __attribute__((ext_vector_type(8))) short short8;
typedef __attribute__((ext_vector_type(4))) float f32x4;

__device__ __forceinline__ float bf2f(unsigned short u) {
    union { unsigned int i; float f; } v; v.i = ((unsigned int)u) << 16; return v.f;
}
__device__ __forceinline__ unsigned short f2bf(float f) {
    union { float f; unsigned int i; } v; v.f = f;
    unsigned int x = v.i;
    return (unsigned short)((x + 0x7fffu + ((x >> 16) & 1u)) >> 16);  // RNE
}
__device__ __forceinline__ int eidx(const int* ei, int i64, int which, int e) {
    int idx = which * N_EDGES + e;
    return i64 ? ei[idx * 2] : ei[idx];
}
__device__ __forceinline__ f32x4 ldx4(const void* xv, int xf32, size_t off) {
    if (xf32) return *(const f32x4*)((const float*)xv + off);
    uint2 u = *(const uint2*)((const unsigned short*)xv + off);
    f32x4 o;
    o[0] = bf2f((unsigned short)(u.x & 0xffffu));
    o[1] = bf2f((unsigned short)(u.x >> 16));
    o[2] = bf2f((unsigned short)(u.y & 0xffffu));
    o[3] = bf2f((unsigned short)(u.y >> 16));
    return o;
}

// ---- fused: dtype detect (block 0) + zero cnt/stats (all blocks) ----
__global__ void k_pre(const unsigned short* __restrict__ xs,
                      const unsigned short* __restrict__ wsw,
                      const int* __restrict__ ei, int* __restrict__ flags,
                      int* __restrict__ cnt, float* __restrict__ stats) {
    int i = blockIdx.x * 256 + threadIdx.x;
    if (i < N_NODES) cnt[i] = 0;
    if (i < 512) stats[i] = 0.0f;
    if (blockIdx.x == 0) {
        __shared__ int red[3];
        int tid = threadIdx.x;
        if (tid < 3) red[tid] = 0;
        __syncthreads();
        int badx = 0, badw = 0, nz = 0;
        for (int j = 0; j < 8; ++j) {
            if (!(fabsf(bf2f(xs[tid * 8 + j])) <= 1000.0f)) badx = 1;
            if (!(fabsf(bf2f(wsw[tid * 8 + j])) <= 1000.0f)) badw = 1;
            if (ei[(tid * 8 + j) * 2 + 1] != 0) nz = 1;
        }
        if (badx) atomicOr(&red[0], 1);
        if (badw) atomicOr(&red[1], 1);
        if (nz)   atomicOr(&red[2], 1);
        __syncthreads();
        if (tid == 0) { flags[0] = red[0]; flags[1] = red[1]; flags[2] = red[2] ? 0 : 1; }
    }
}

__global__ void k_cnt(const int* __restrict__ ei, int* __restrict__ cnt,
                      const int* __restrict__ flags) {
    int i64 = flags[2];
    int e = blockIdx.x * 256 + threadIdx.x;
    if (e < N_EDGES) atomicAdd(&cnt[eidx(ei, i64, 1, e)], 1);
}

// ---- per-chunk sums (512 nodes/block) ----
__global__ void k_scan1(const int* __restrict__ cnt, int* __restrict__ partial) {
    __shared__ int red[256];
    int t = threadIdx.x, b = blockIdx.x;
    int i0 = b * 512 + t * 2;
    int s = 0;
    if (i0 < N_NODES) s += cnt[i0];
    if (i0 + 1 < N_NODES) s += cnt[i0 + 1];
    red[t] = s;
    __syncthreads();
    for (int off = 128; off > 0; off >>= 1) {
        if (t < off) red[t] += red[t + off];
        __syncthreads();
    }
    if (t == 0) partial[b] = red[0];
}

// ---- fused: scan partials + local scan + row_start/cursor/dinv ----
__global__ void k_scan23(const int* __restrict__ cnt, const int* __restrict__ partial,
                         int* __restrict__ row_start, int* __restrict__ cursor,
                         float* __restrict__ dinv) {
    __shared__ int ps[256];
    __shared__ int s[512];
    int t = threadIdx.x, b = blockIdx.x;
    if (t < 256) ps[t] = (t < 200) ? partial[t] : 0;
    __syncthreads();
    for (int off = 1; off < 256; off <<= 1) {
        int u = (t >= off && t < 256) ? ps[t - off] : 0;
        __syncthreads();
        if (t < 256) ps[t] += u;
        __syncthreads();
    }
    int pbase = (b == 0) ? 0 : ps[b - 1];   // exclusive block base
    int i = b * 512 + t;
    int v = (i < N_NODES) ? cnt[i] : 0;
    s[t] = v;
    __syncthreads();
    for (int off = 1; off < 512; off <<= 1) {
        int u = (t >= off) ? s[t - off] : 0;
        __syncthreads();
        s[t] += u;
        __syncthreads();
    }
    if (i < N_NODES) {
        int excl = pbase + s[t] - v;
        row_start[i] = excl;
        cursor[i] = excl;
        dinv[i] = rsqrtf((float)v + 1.0f);   // +1 self-loop
    }
}

__global__ void k_fill(const int* __restrict__ ei, const float* __restrict__ dinv,
                       int* __restrict__ cursor, int* __restrict__ csr_src,
                       float* __restrict__ csr_nrm, const int* __restrict__ flags) {
    int i64 = flags[2];
    int e = blockIdx.x * 256 + threadIdx.x;
    if (e >= N_EDGES) return;
    int c = eidx(ei, i64, 1, e);
    int r = eidx(ei, i64, 0, e);
    int slot = atomicAdd(&cursor[c], 1);
    csr_src[slot] = r;
    csr_nrm[slot] = dinv[r] * dinv[c];
}

// ---- W -> transposed split-bf16 (hi + lo) ----
__global__ void k_wt(const void* __restrict__ wv, unsigned short* __restrict__ Wth,
                     unsigned short* __restrict__ Wtl, const int* __restrict__ flags) {
    int wf32 = flags[1];
    int k = blockIdx.x, n = threadIdx.x;
    float v = wf32 ? ((const float*)wv)[k * DIM + n]
                   : bf2f(((const unsigned short*)wv)[k * DIM + n]);
    unsigned short h = f2bf(v);
    Wth[(size_t)n * DIM + k] = h;
    Wtl[(size_t)n * DIM + k] = f2bf(v - bf2f(h));
}

// ---- aggregation: one wave/node, 4-way MLP-batched gather, emit split-bf16 z ----
__global__ void k_agg(const void* __restrict__ xv, const int* __restrict__ row_start,
                      const int* __restrict__ cnt, const int* __restrict__ csr_src,
                      const float* __restrict__ csr_nrm, const float* __restrict__ dinv,
                      unsigned short* __restrict__ zh, unsigned short* __restrict__ zl,
                      const int* __restrict__ flags, int base) {
    int xf32 = flags[0];
    int gid = blockIdx.x * 256 + threadIdx.x;
    int node = base + (gid >> 6);
    int lane = gid & 63;
    float dv = dinv[node];
    float s = dv * dv;
    f32x4 acc = ldx4(xv, xf32, (size_t)node * DIM + lane * 4);
    acc[0] *= s; acc[1] *= s; acc[2] *= s; acc[3] *= s;
    int start = row_start[node];
    int len = cnt[node];                         // wave-uniform
    int j = 0;
    for (; j + 3 < len; j += 4) {                // 4 independent gathers in flight
        int s0 = csr_src[start + j], s1 = csr_src[start + j + 1];
        int s2 = csr_src[start + j + 2], s3 = csr_src[start + j + 3];
        float n0 = csr_nrm[start + j], n1 = csr_nrm[start + j + 1];
        float n2 = csr_nrm[start + j + 2], n3 = csr_nrm[start + j + 3];
        f32x4 a0 = ldx4(xv, xf32, (size_t)s0 * DIM + lane * 4);
        f32x4 a1 = ldx4(xv, xf32, (size_t)s1 * DIM + lane * 4);
        f32x4 a2 = ldx4(xv, xf32, (size_t)s2 * DIM + lane * 4);
        f32x4 a3 = ldx4(xv, xf32, (size_t)s3 * DIM + lane * 4);
        #pragma unroll
        for (int q = 0; q < 4; ++q) {
            acc[q] += n0 * a0[q]; acc[q] += n1 * a1[q];
            acc[q] += n2 * a2[q]; acc[q] += n3 * a3[q];
        }
    }
    for (; j < len; ++j) {
        int src = csr_src[start + j];
        float nrm = csr_nrm[start + j];
        f32x4 xr = ldx4(xv, xf32, (size_t)src * DIM + lane * 4);
        #pragma unroll
        for (int q = 0; q < 4; ++q) acc[q] += nrm * xr[q];
    }
    // emit split-bf16
    uint2 ph, pl;
    unsigned short h0 = f2bf(acc[0]), h1 = f2bf(acc[1]), h2 = f2bf(acc[2]), h3 = f2bf(acc[3]);
    ph.x = (unsigned int)h0 | ((unsigned int)h1 << 16);
    ph.y = (unsigned int)h2 | ((unsigned int)h3 << 16);
    pl.x = (unsigned int)f2bf(acc[0] - bf2f(h0)) | ((unsigned int)f2bf(acc[1] - bf2f(h1)) << 16);
    pl.y = (unsigned int)f2bf(acc[2] - bf2f(h2)) | ((unsigned int)f2bf(acc[3] - bf2f(h3)) << 16);
    size_t zo = (size_t)(node - base) * DIM + lane * 4;
    *(uint2*)(zh + zo) = ph;
    *(uint2*)(zl + zo) = pl;
}

// ---- GEMM: out0 = z @ W, LDS-free, direct global fragment loads, fused BN stats ----
// 512 threads; M-tile 80; wave w covers cols w*32..w*32+31 (nt 0..1)
__launch_bounds__(512)
__global__ void k_gemm(const unsigned short* __restrict__ zh, const unsigned short* __restrict__ zl,
                       const unsigned short* __restrict__ Wth, const unsigned short* __restrict__ Wtl,
                       float* __restrict__ outF, unsigned short* __restrict__ outH,
                       float* __restrict__ stats, int base) {
    __shared__ float bs[512];
    int tid = threadIdx.x;
    bs[tid] = 0.0f;
    __syncthreads();
    int m0l = blockIdx.x * 80;
    int w = tid >> 6, lane = tid & 63, quad = lane >> 4, rl = lane & 15;
    f32x4 acc[5][2];
    #pragma unroll
    for (int ms = 0; ms < 5; ++ms)
        #pragma unroll
        for (int nt = 0; nt < 2; ++nt)
            acc[ms][nt] = (f32x4){0.f, 0.f, 0.f, 0.f};
    #pragma unroll
    for (int kk = 0; kk < 8; ++kk) {
        int k0 = kk * 32 + quad * 8;
        short8 bh[2], bl[2];
        #pragma unroll
        for (int nt = 0; nt < 2; ++nt) {
            int n = w * 32 + nt * 16 + rl;
            bh[nt] = *(const short8*)(Wth + (size_t)n * DIM + k0);
            bl[nt] = *(const short8*)(Wtl + (size_t)n * DIM + k0);
        }
        #pragma unroll
        for (int ms = 0; ms < 5; ++ms) {
            size_t ro = (size_t)(m0l + ms * 16 + rl) * DIM + k0;
            short8 ah = *(const short8*)(zh + ro);   // A[m=rl][k=quad*8+j] — 4 quads share one 64B line
            short8 al = *(const short8*)(zl + ro);
            #pragma unroll
            for (int nt = 0; nt < 2; ++nt) {
                acc[ms][nt] = __builtin_amdgcn_mfma_f32_16x16x32_bf16(ah, bh[nt], acc[ms][nt], 0, 0, 0);
                acc[ms][nt] = __builtin_amdgcn_mfma_f32_16x16x32_bf16(al, bh[nt], acc[ms][nt], 0, 0, 0);
                acc[ms][nt] = __builtin_amdgcn_mfma_f32_16x16x32_bf16(ah, bl[nt], acc[ms][nt], 0, 0, 0);
            }
        }
    }
    // C/D: col = lane&15, row = quad*4 + reg
    #pragma unroll
    for (int nt = 0; nt < 2; ++nt) {
        int col = w * 32 + nt * 16 + rl;
        float s1 = 0.f, s2 = 0.f;
        #pragma unroll
        for (int ms = 0; ms < 5; ++ms)
            #pragma unroll
            for (int i = 0; i < 4; ++i) {
                float v = acc[ms][nt][i];
                s1 += v; s2 += v * v;
                size_t go = (size_t)(base + m0l + ms * 16 + quad * 4 + i) * DIM + col;
                if (outH) outH[go] = f2bf(v);
                else outF[go] = v;
            }
        atomicAdd(&bs[col], s1);
        atomicAdd(&bs[256 + col], s2);
    }
    __syncthreads();
    atomicAdd(&stats[tid], bs[tid]);
}

// ---- fused BN-fold + normalize + tanh; reads bf16 out0 (or fp32 in-place) ----
__global__ void k_final(const unsigned short* __restrict__ outH, float* __restrict__ out,
                        const float* __restrict__ stats, const void* __restrict__ gv,
                        const void* __restrict__ bv, const int* __restrict__ flags) {
    __shared__ float scsh[512];
    int tid = threadIdx.x;
    {   // per-block scale/shift recompute (stats are tiny + L2-broadcast)
        int ff32 = flags[0];
        const float invN = 1.0f / (float)N_NODES;
        float mean = stats[tid & 255] * invN;
        float var = stats[256 + (tid & 255)] * invN - mean * mean;
        float g = ff32 ? ((const float*)gv)[tid & 255] : bf2f(((const unsigned short*)gv)[tid & 255]);
        float bb = ff32 ? ((const float*)bv)[tid & 255] : bf2f(((const unsigned short*)bv)[tid & 255]);
        float sc = g * rsqrtf(var + BN_EPS);
        scsh[tid & 255] = sc;
        scsh[256 + (tid & 255)] = bb - mean * sc;
    }
    __syncthreads();
    int t = blockIdx.x * 256 + tid;
    int f0 = (t & 63) * 4;
    size_t off = (size_t)t * 4;
    f32x4 v;
    if (outH) {
        uint2 u = *(const uint2*)(outH + off);
        v[0] = bf2f((unsigned short)(u.x & 0xffffu));
        v[1] = bf2f((unsigned short)(u.x >> 16));
        v[2] = bf2f((unsigned short)(u.y & 0xffffu));
        v[3] = bf2f((unsigned short)(u.y >> 16));
    } else {
        v = *(const f32x4*)(out + off);
    }
    f32x4 o;
    #pragma unroll
    for (int j = 0; j < 4; ++j)
        o[j] = tanhf(v[j] * scsh[f0 + j] + scsh[256 + f0 + j]);
    *(f32x4*)(out + off) = o;
}

extern "C" void kernel_launch(void* const* d_in, const int* in_sizes, int n_in,
                              void* d_out, int out_size, void* d_ws, size_t ws_size,
                              hipStream_t stream) {
    const void* x     = d_in[0];
    const void* W     = d_in[1];
    // d_in[2] = b: cancelled exactly by BatchNorm. Unused.
    const void* gamma = d_in[3];
    const void* beta  = d_in[4];
    const int* ei     = (const int*)d_in[5];
    float* out = (float*)d_out;   // fp32 output (validated)

    char* ws = (char*)d_ws;
    int*   flags     = (int*)(ws);
    int*   cnt       = (int*)(ws + 4096);
    int*   row_start = (int*)(ws + 409600);
    int*   cursor    = (int*)(ws + 819200);
    float* dinv      = (float*)(ws + 1228800);
    int*   partial   = (int*)(ws + 1638400);
    float* stats     = (float*)(ws + 1654784);
    unsigned short* Wth = (unsigned short*)(ws + 1671168);
    unsigned short* Wtl = (unsigned short*)(ws + 1802240);
    int*   csr_src   = (int*)(ws + 1933312);
    float* csr_nrm   = (float*)(ws + 3215360);
    const size_t o_out0h = 4497408;                       // 51.2 MB bf16 out0
    const size_t zA = o_out0h + 51200000;                 // z after out0h (bf16 path)
    const size_t zB = o_out0h;                            // z here if fp32 fallback

    // choose bf16-out0 path if ws is big enough to keep chunking coarse
    long long rowsA = (ws_size > zA) ? (long long)((ws_size - zA) / 1024) : 0;  // zh+zl = 1024 B/row
    rowsA -= rowsA % 80;
    int useH = (rowsA >= 25000);
    size_t zoff = useH ? zA : zB;
    long long maxRows = (ws_size > zoff) ? (long long)((ws_size - zoff) / 1024) : 0;
    maxRows -= maxRows % 80;
    if (maxRows <= 0) maxRows = 80;
    if (maxRows > N_NODES) maxRows = N_NODES;
    unsigned short* out0h = useH ? (unsigned short*)(ws + o_out0h) : (unsigned short*)0;

    k_pre   <<<391,  256, 0, stream>>>((const unsigned short*)x, (const unsigned short*)W,
                                       ei, flags, cnt, stats);
    k_cnt   <<<1250, 256, 0, stream>>>(ei, cnt, flags);
    k_scan1 <<<200,  256, 0, stream>>>(cnt, partial);
    k_scan23<<<200,  512, 0, stream>>>(cnt, partial, row_start, cursor, dinv);
    k_fill  <<<1250, 256, 0, stream>>>(ei, dinv, cursor, csr_src, csr_nrm, flags);
    k_wt    <<<256,  256, 0, stream>>>(W, Wth, Wtl, flags);

    for (int base = 0; base < N_NODES; base += (int)maxRows) {
        int count = N_NODES - base;
        if (count > (int)maxRows) count = (int)maxRows;   // multiple of 80
        unsigned short* zh = (unsigned short*)(ws + zoff);
        unsigned short* zl = zh + (size_t)maxRows * DIM;
        k_agg <<<count / 4,  256, 0, stream>>>(x, row_start, cnt, csr_src, csr_nrm,
                                               dinv, zh, zl, flags, base);
        k_gemm<<<count / 80, 512, 0, stream>>>(zh, zl, Wth, Wtl, out, out0h, stats, base);
    }

    k_final<<<25000, 256, 0, stream>>>(out0h, out, stats, gamma, beta, flags);
}